// Round 1
// baseline (1190.703 us; speedup 1.0000x reference)
//
#include <hip/hip_runtime.h>

#define BB 16
#define SS 4096
#define SC 4097
#define DD 1024
#define HH 16

__device__ __forceinline__ float dot4(const float4 a, const float4 b) {
  return a.x*b.x + a.y*b.y + a.z*b.z + a.w*b.w;
}
__device__ __forceinline__ void fma2(float2& a, const float w, const float2 v) {
  a.x = fmaf(w, v.x, a.x); a.y = fmaf(w, v.y, a.y);
}
__device__ __forceinline__ void add4(float4& a, const float4 v) {
  a.x += v.x; a.y += v.y; a.z += v.z; a.w += v.w;
}
__device__ __forceinline__ unsigned short f2bf(float x) {
  unsigned int u = __float_as_uint(x);
  u += 0x7fffu + ((u >> 16) & 1u);   // RNE
  return (unsigned short)(u >> 16);
}

typedef float f32x4 __attribute__((ext_vector_type(4)));
typedef float f32x2 __attribute__((ext_vector_type(2)));
__device__ __forceinline__ void nt_store4(float4* p, const float4 v) {
  f32x4 t = {v.x, v.y, v.z, v.w};
  __builtin_nontemporal_store(t, (f32x4*)p);
}
__device__ __forceinline__ void nt_store2(float2* p, const float2 v) {
  f32x2 t = {v.x, v.y};
  __builtin_nontemporal_store(t, (f32x2*)p);
}

// ---------------------------------------------------------------------------
// gemv16: Y[b,d] = (sum_e X[b,e] * W[d,e] + bias[d]) * scale   (unchanged)
// ---------------------------------------------------------------------------
__global__ __launch_bounds__(256, 1) void gemv16(
    const float* __restrict__ X, const float* __restrict__ W,
    const float* __restrict__ bias, const float scale,
    float* __restrict__ Y, const int hsel)
{
  __shared__ float4 xs[4096];
  const int blk = blockIdx.x, t = threadIdx.x;
  const int tp = t >> 4, te = t & 15;
  for (int b = 0; b < BB; ++b) {
    const float* xrow = hsel ? (X + (size_t)(b * 16 + (blk >> 2)) * DD)
                             : (X + (size_t)b * DD);
    xs[b * 256 + tp * 16 + (te ^ (tp & 7))] = ((const float4*)xrow)[t];
  }
  __syncthreads();
  const int dl = tp, part = te;
  const int d = blk * 16 + dl;
  const int sw = part & 7;
  const float4* wrow = (const float4*)(W + (size_t)d * DD) + part * 16;
  float a[BB];
#pragma unroll
  for (int b = 0; b < BB; ++b) a[b] = 0.f;
#pragma unroll
  for (int e4 = 0; e4 < 16; ++e4) {
    const float4 w4 = wrow[e4];
#pragma unroll
    for (int b = 0; b < BB; ++b)
      a[b] += dot4(w4, xs[b * 256 + part * 16 + (e4 ^ sw)]);
  }
#pragma unroll
  for (int b = 0; b < BB; ++b) {
    float v = a[b];
    v += __shfl_xor(v, 1, 64);
    v += __shfl_xor(v, 2, 64);
    v += __shfl_xor(v, 4, 64);
    v += __shfl_xor(v, 8, 64);
    a[b] = v;
  }
  if (part == 0) {
    const float bs = bias[d];
#pragma unroll
    for (int b = 0; b < BB; ++b)
      Y[(size_t)b * DD + d] = (a[b] + bs) * scale;
  }
}

// ---------------------------------------------------------------------------
// qw_kernel: qwbf[b,h,e] = bf16( sum_dh q[b, h*64+dh] * wk[h*64+dh, e] )
// ---------------------------------------------------------------------------
__global__ __launch_bounds__(256, 1) void qw_kernel(
    const float* __restrict__ q, const float* __restrict__ w_in,
    unsigned short* __restrict__ qwbf)
{
  __shared__ float qh[BB * 64];
  const int h = blockIdx.x >> 2, et = blockIdx.x & 3;
  const int t = threadIdx.x;
#pragma unroll
  for (int k = 0; k < 4; ++k) {
    const int i = t + 256 * k;
    qh[i] = q[(i >> 6) * DD + h * 64 + (i & 63)];
  }
  __syncthreads();
  const int e = et * 256 + t;
  const float* wk = w_in + (size_t)(DD + h * 64) * DD + e;
  float a[BB];
#pragma unroll
  for (int b = 0; b < BB; ++b) a[b] = 0.f;
  for (int dh = 0; dh < 64; ++dh) {
    const float wv = wk[(size_t)dh * DD];
#pragma unroll
    for (int b = 0; b < BB; ++b) a[b] = fmaf(qh[b * 64 + dh], wv, a[b]);
  }
#pragma unroll
  for (int b = 0; b < BB; ++b)
    qwbf[(size_t)(b * HH + h) * DD + e] = f2bf(a[b]);
}

// ---------------------------------------------------------------------------
// attn_main v2: 512 threads, fully phase-separated.
//   Phase 1: all RPC rows -> scores -> exp weights into LDS Wl (K copy fused).
//   Phase 2: all RPC rows -> weighted V accumulation (V copy fused),
//            each thread owns 2 value dims (float2), acc[16] = 32 VGPR.
//   Row-weight sums l[h] recomputed from Wl at the end (no per-row lacc adds).
// ---------------------------------------------------------------------------
template<int CPB>
__global__ __launch_bounds__(512, 4) void attn_main(
    const float* __restrict__ past_key, const float* __restrict__ past_value,
    const float* __restrict__ key_in, const float* __restrict__ value_in,
    const unsigned short* __restrict__ qwbf,
    float* __restrict__ out_ck, float* __restrict__ out_cv,
    float* __restrict__ pvp, float* __restrict__ lp)
{
  constexpr int RPC = SS / CPB;     // rows per block
  constexpr int RPW = RPC / 8;      // rows per wave (phase 1)
  __shared__ uint2 qws[HH * 256];            // bf16 qw for this batch, 32 KB
  __shared__ float4 Wl[(RPC + 1) * 4];       // exp weights [row][h/4]

  const int blk = blockIdx.x;
  const int b = blk / CPB, c = blk % CPB;
  const int t = threadIdx.x, wave = t >> 6, lane = t & 63;
  const int gbase = c * RPC;

  {
    const uint2* src = (const uint2*)qwbf + (size_t)b * (HH * 256);
#pragma unroll
    for (int i = 0; i < 8; ++i) qws[t + 512 * i] = src[t + 512 * i];
  }

  const float4* pk4 = (const float4*)past_key;
  float4* ck4 = (float4*)out_ck;
  __syncthreads();

  // ---- phase 1: scores + exp for all RPC rows; fused K copy ----
  for (int bt = 0; bt < RPW / 2; ++bt) {
    const int lr = wave * RPW + bt * 2;       // local row (pair base)
    const int r0 = gbase + lr;
    float4 k0[4], k1[4];
    const size_t base0 = (size_t)(b * SS + r0) * 256 + lane;
#pragma unroll
    for (int j = 0; j < 4; ++j) k0[j] = pk4[base0 + j * 64];
#pragma unroll
    for (int j = 0; j < 4; ++j) k1[j] = pk4[base0 + 256 + j * 64];
    const size_t cb0 = (size_t)(b * SC + r0) * 256 + lane;
#pragma unroll
    for (int j = 0; j < 4; ++j) nt_store4(&ck4[cb0 + j * 64], k0[j]);
#pragma unroll
    for (int j = 0; j < 4; ++j) nt_store4(&ck4[cb0 + 256 + j * 64], k1[j]);

    float p0[HH], p1[HH];
#pragma unroll
    for (int h = 0; h < HH; ++h) { p0[h] = 0.f; p1[h] = 0.f; }
#pragma unroll
    for (int j = 0; j < 4; ++j) {
#pragma unroll
      for (int h = 0; h < HH; ++h) {
        const uint2 q2 = qws[h * 256 + j * 64 + lane];
        const float f0 = __uint_as_float(q2.x << 16);
        const float f1 = __uint_as_float(q2.x & 0xffff0000u);
        const float f2 = __uint_as_float(q2.y << 16);
        const float f3 = __uint_as_float(q2.y & 0xffff0000u);
        p0[h] += k0[j].x * f0 + k0[j].y * f1 + k0[j].z * f2 + k0[j].w * f3;
        p1[h] += k1[j].x * f0 + k1[j].y * f1 + k1[j].z * f2 + k1[j].w * f3;
      }
    }
#pragma unroll
    for (int h = 0; h < HH; ++h) {
      float v0 = p0[h], v1 = p1[h];
      v0 += __shfl_xor(v0, 32, 64); v1 += __shfl_xor(v1, 32, 64);
      v0 += __shfl_xor(v0, 16, 64); v1 += __shfl_xor(v1, 16, 64);
      v0 += __shfl_xor(v0, 8, 64);  v1 += __shfl_xor(v1, 8, 64);
      v0 += __shfl_xor(v0, 4, 64);  v1 += __shfl_xor(v1, 4, 64);
      v0 += __shfl_xor(v0, 2, 64);  v1 += __shfl_xor(v1, 2, 64);
      v0 += __shfl_xor(v0, 1, 64);  v1 += __shfl_xor(v1, 1, 64);
      p0[h] = v0; p1[h] = v1;
    }
    float e[HH];
#pragma unroll
    for (int h = 0; h < HH; ++h) e[h] = __expf((lane & 1) ? p1[h] : p0[h]);
    if (lane < 2) {
      const int wr = lr + lane;
      Wl[wr * 4 + 0] = make_float4(e[0],  e[1],  e[2],  e[3]);
      Wl[wr * 4 + 1] = make_float4(e[4],  e[5],  e[6],  e[7]);
      Wl[wr * 4 + 2] = make_float4(e[8],  e[9],  e[10], e[11]);
      Wl[wr * 4 + 3] = make_float4(e[12], e[13], e[14], e[15]);
    }
  }
  __syncthreads();

  // ---- phase 2: fused V copy + weighted accumulation (thread owns 2 dims) --
  const float2* pv2 = (const float2*)past_value;
  float2* cv2 = (float2*)out_cv;
  float2 acc[HH];
#pragma unroll
  for (int h = 0; h < HH; ++h) acc[h] = make_float2(0.f, 0.f);

  const size_t vbase = (size_t)(b * SS + gbase) * 512 + t;
  const size_t cvb   = (size_t)(b * SC + gbase) * 512 + t;
  float2 va[4], vb[4];
#pragma unroll
  for (int r = 0; r < 4; ++r) va[r] = pv2[vbase + (size_t)r * 512];
  for (int i0 = 0; i0 < RPC; i0 += 8) {
#pragma unroll
    for (int r = 0; r < 4; ++r) vb[r] = pv2[vbase + (size_t)(i0 + 4 + r) * 512];
#pragma unroll
    for (int r = 0; r < 4; ++r) {
      const int i = i0 + r;
      nt_store2(&cv2[cvb + (size_t)i * 512], va[r]);
      const float4 w0 = Wl[i * 4 + 0], w1 = Wl[i * 4 + 1];
      const float4 w2 = Wl[i * 4 + 2], w3 = Wl[i * 4 + 3];
      fma2(acc[0],  w0.x, va[r]); fma2(acc[1],  w0.y, va[r]);
      fma2(acc[2],  w0.z, va[r]); fma2(acc[3],  w0.w, va[r]);
      fma2(acc[4],  w1.x, va[r]); fma2(acc[5],  w1.y, va[r]);
      fma2(acc[6],  w1.z, va[r]); fma2(acc[7],  w1.w, va[r]);
      fma2(acc[8],  w2.x, va[r]); fma2(acc[9],  w2.y, va[r]);
      fma2(acc[10], w2.z, va[r]); fma2(acc[11], w2.w, va[r]);
      fma2(acc[12], w3.x, va[r]); fma2(acc[13], w3.y, va[r]);
      fma2(acc[14], w3.z, va[r]); fma2(acc[15], w3.w, va[r]);
    }
    if (i0 + 8 < RPC) {
#pragma unroll
      for (int r = 0; r < 4; ++r) va[r] = pv2[vbase + (size_t)(i0 + 8 + r) * 512];
    }
#pragma unroll
    for (int r = 0; r < 4; ++r) {
      const int i = i0 + 4 + r;
      nt_store2(&cv2[cvb + (size_t)i * 512], vb[r]);
      const float4 w0 = Wl[i * 4 + 0], w1 = Wl[i * 4 + 1];
      const float4 w2 = Wl[i * 4 + 2], w3 = Wl[i * 4 + 3];
      fma2(acc[0],  w0.x, vb[r]); fma2(acc[1],  w0.y, vb[r]);
      fma2(acc[2],  w0.z, vb[r]); fma2(acc[3],  w0.w, vb[r]);
      fma2(acc[4],  w1.x, vb[r]); fma2(acc[5],  w1.y, vb[r]);
      fma2(acc[6],  w1.z, vb[r]); fma2(acc[7],  w1.w, vb[r]);
      fma2(acc[8],  w2.x, vb[r]); fma2(acc[9],  w2.y, vb[r]);
      fma2(acc[10], w2.z, vb[r]); fma2(acc[11], w2.w, vb[r]);
      fma2(acc[12], w3.x, vb[r]); fma2(acc[13], w3.y, vb[r]);
      fma2(acc[14], w3.z, vb[r]); fma2(acc[15], w3.w, vb[r]);
    }
  }

  // ---- new token (row 4096) from key/value inputs ----
  if (c == CPB - 1) {
    if (wave == 0) {
      float p[HH];
#pragma unroll
      for (int h = 0; h < HH; ++h) p[h] = 0.f;
#pragma unroll
      for (int j = 0; j < 4; ++j) {
        const float4 k4 = ((const float4*)key_in)[b * 256 + j * 64 + lane];
        nt_store4(&ck4[(size_t)(b * SC + SS) * 256 + j * 64 + lane], k4);
#pragma unroll
        for (int h = 0; h < HH; ++h) {
          const uint2 q2 = qws[h * 256 + j * 64 + lane];
          const float f0 = __uint_as_float(q2.x << 16);
          const float f1 = __uint_as_float(q2.x & 0xffff0000u);
          const float f2 = __uint_as_float(q2.y << 16);
          const float f3 = __uint_as_float(q2.y & 0xffff0000u);
          p[h] += k4.x * f0 + k4.y * f1 + k4.z * f2 + k4.w * f3;
        }
      }
#pragma unroll
      for (int h = 0; h < HH; ++h) {
        float v = p[h];
        v += __shfl_xor(v, 32, 64);
        v += __shfl_xor(v, 16, 64);
        v += __shfl_xor(v, 8, 64);
        v += __shfl_xor(v, 4, 64);
        v += __shfl_xor(v, 2, 64);
        v += __shfl_xor(v, 1, 64);
        p[h] = v;
      }
      if (lane == 0) {
        Wl[RPC * 4 + 0] = make_float4(__expf(p[0]),  __expf(p[1]),  __expf(p[2]),  __expf(p[3]));
        Wl[RPC * 4 + 1] = make_float4(__expf(p[4]),  __expf(p[5]),  __expf(p[6]),  __expf(p[7]));
        Wl[RPC * 4 + 2] = make_float4(__expf(p[8]),  __expf(p[9]),  __expf(p[10]), __expf(p[11]));
        Wl[RPC * 4 + 3] = make_float4(__expf(p[12]), __expf(p[13]), __expf(p[14]), __expf(p[15]));
      }
    }
    __syncthreads();
    const float2 v2 = ((const float2*)value_in)[b * 512 + t];
    nt_store2(&cv2[(size_t)(b * SC + SS) * 512 + t], v2);
    const float4 w0 = Wl[RPC * 4 + 0], w1 = Wl[RPC * 4 + 1];
    const float4 w2 = Wl[RPC * 4 + 2], w3 = Wl[RPC * 4 + 3];
    fma2(acc[0],  w0.x, v2); fma2(acc[1],  w0.y, v2);
    fma2(acc[2],  w0.z, v2); fma2(acc[3],  w0.w, v2);
    fma2(acc[4],  w1.x, v2); fma2(acc[5],  w1.y, v2);
    fma2(acc[6],  w1.z, v2); fma2(acc[7],  w1.w, v2);
    fma2(acc[8],  w2.x, v2); fma2(acc[9],  w2.y, v2);
    fma2(acc[10], w2.z, v2); fma2(acc[11], w2.w, v2);
    fma2(acc[12], w3.x, v2); fma2(acc[13], w3.y, v2);
    fma2(acc[14], w3.z, v2); fma2(acc[15], w3.w, v2);
  }

  // ---- row-weight sums l[h] from Wl (wave 0) ----
  if (wave == 0) {
    const int h = lane & 15, q = lane >> 4;   // 4 row-stripes per h
    float s = 0.f;
    const float* Wf = (const float*)Wl;
    const int nrows = RPC + ((c == CPB - 1) ? 1 : 0);
    for (int i = q; i < nrows; i += 4) s += Wf[i * 16 + h];
    s += __shfl_xor(s, 16, 64);
    s += __shfl_xor(s, 32, 64);
    if (lane < 16) lp[(size_t)blk * HH + lane] = s;
  }

  // ---- per-block partials (re-read by combine: keep cached, no NT) ----
  float2* pp = (float2*)pvp + (size_t)blk * (HH * 512);
#pragma unroll
  for (int h = 0; h < HH; ++h) pp[h * 512 + t] = acc[h];
}

// ---------------------------------------------------------------------------
// combine: pv_norm[b,h,:] = (sum_c pv_partial) / (sum_c l_partial)  (unchanged)
// ---------------------------------------------------------------------------
template<int CPB>
__global__ __launch_bounds__(256, 1) void combine_kernel(
    const float* __restrict__ pvp, const float* __restrict__ lp,
    float* __restrict__ pvn)
{
  const int blk = blockIdx.x;      // b*16 + h
  const int b = blk >> 4, h = blk & 15;
  const int t = threadIdx.x;
  float4 s = make_float4(0.f, 0.f, 0.f, 0.f);
  float l = 0.f;
  for (int c = 0; c < CPB; ++c) {
    const float4* p = (const float4*)pvp + ((size_t)(b * CPB + c) * HH + h) * 256;
    add4(s, p[t]);
    l += lp[(b * CPB + c) * HH + h];
  }
  const float inv = 1.f / l;
  s.x *= inv; s.y *= inv; s.z *= inv; s.w *= inv;
  ((float4*)pvn)[(size_t)blk * 256 + t] = s;
}

// ---------------------------------------------------------------------------
extern "C" void kernel_launch(void* const* d_in, const int* in_sizes, int n_in,
                              void* d_out, int out_size, void* d_ws, size_t ws_size,
                              hipStream_t stream)
{
  const float* query      = (const float*)d_in[0];
  const float* key_in     = (const float*)d_in[1];
  const float* value_in   = (const float*)d_in[2];
  const float* past_key   = (const float*)d_in[3];
  const float* past_value = (const float*)d_in[4];
  const float* w_in       = (const float*)d_in[5];
  const float* b_in       = (const float*)d_in[6];
  const float* w_out      = (const float*)d_in[7];
  const float* b_out      = (const float*)d_in[8];

  float* out    = (float*)d_out;                       // 16 x 1024
  float* out_ck = out + (size_t)BB * DD;               // 16 x 4097 x 1024
  float* out_cv = out_ck + (size_t)BB * SC * DD;       // 16 x 4097 x 1024

  float* ws = (float*)d_ws;
  float* ws_q = ws;                                              // 16384 f
  unsigned short* ws_qwbf = (unsigned short*)(ws_q + BB * DD);   // 262144 bf16
  float* ws_pvn = ws_q + BB * DD + (BB * HH * DD) / 2;           // 262144 f
  float* ws_ctx = ws_pvn + (size_t)BB * HH * DD;                 // 16384 f
  float* ws_pvp = ws_ctx + BB * DD;                              // partials

  const size_t fixed_f = (size_t)BB * DD + (size_t)(BB * HH * DD) / 2
                       + (size_t)BB * HH * DD + (size_t)BB * DD;
  const size_t need512 = (fixed_f + (size_t)512 * HH * DD + (size_t)512 * HH)
                       * sizeof(float);
  const int big = (ws_size >= need512) ? 1 : 0;   // ws_size constant -> same path every call

  // q = (query @ wq.T + bq) * hd^-0.5
  gemv16<<<64, 256, 0, stream>>>(query, w_in, b_in, 0.125f, ws_q, 0);
  // qw[b,h,:] = q_head @ wk_head   (bf16-stored)
  qw_kernel<<<64, 256, 0, stream>>>(ws_q, w_in, ws_qwbf);

  if (big) {
    float* ws_lp = ws_pvp + (size_t)512 * HH * DD;
    attn_main<32><<<512, 512, 0, stream>>>(past_key, past_value, key_in, value_in,
                                           ws_qwbf, out_ck, out_cv, ws_pvp, ws_lp);
    combine_kernel<32><<<256, 256, 0, stream>>>(ws_pvp, ws_lp, ws_pvn);
  } else {
    float* ws_lp = ws_pvp + (size_t)256 * HH * DD;
    attn_main<16><<<256, 512, 0, stream>>>(past_key, past_value, key_in, value_in,
                                           ws_qwbf, out_ck, out_cv, ws_pvp, ws_lp);
    combine_kernel<16><<<256, 256, 0, stream>>>(ws_pvp, ws_lp, ws_pvn);
  }

  // ctx[b,d] = pv_norm[b, h(d), :] . wv[d,:] + bv[d]
  gemv16<<<64, 256, 0, stream>>>(ws_pvn, w_in + 2 * DD * DD, b_in + 2 * DD, 1.0f, ws_ctx, 1);
  // out = ctx @ w_out.T + b_out
  gemv16<<<64, 256, 0, stream>>>(ws_ctx, w_out, b_out, 1.0f, out, 0);
}